// Round 15
// baseline (104.237 us; speedup 1.0000x reference)
//
#include <hip/hip_runtime.h>
#include <stdint.h>

// minerva2: echo = (F̂ Ê^T)^3 @ V, intensity = rowsum((F̂ Ê^T)^3)
// R15 = R14 (64-row D-tiles, R12-proven zero-conflict sub-slab layout) with
// register diet to fit <=128 TOTAL VGPRs (arch + acc) -> 4 waves/SIMD:
//   B[4] -> two B-pairs (live temps halved), __launch_bounds__(256,4).

typedef unsigned short u16;
typedef __bf16 bf16x8 __attribute__((ext_vector_type(8)));
typedef float f32x4 __attribute__((ext_vector_type(4)));
typedef unsigned short u16x4 __attribute__((ext_vector_type(4)));

#define NQ 8192
#define ND 16384
#define NH 256
#define NC 28
#define DCHUNK 1024
#define NDT 16       // 64-row D-tiles per chunk
#define NSLOT 16     // partial slots = 16 D-chunks

__device__ __forceinline__ u16 f2bf(float f) {
  unsigned u = __builtin_bit_cast(unsigned, f);
  u += 0x7fffu + ((u >> 16) & 1u);   // RNE
  return (u16)(u >> 16);
}

__device__ __forceinline__ unsigned cvtpk(float lo, float hi) {
  unsigned r;
  asm("v_cvt_pk_bf16_f32 %0, %1, %2" : "=v"(r) : "v"(lo), "v"(hi));
  return r;  // low16 = bf16(lo), high16 = bf16(hi)  (RNE)
}

// After: x = [x.r0, x.r2, y.r0, y.r2] (by 16-lane row), y = [x.r1, x.r3, y.r1, y.r3]
__device__ __forceinline__ void swap2(unsigned& x, unsigned& y) {
  asm("v_permlane32_swap_b32 %0, %1" : "+v"(x), "+v"(y));  // x.r23 <-> y.r01
  asm("v_permlane16_swap_b32 %0, %1" : "+v"(x), "+v"(y));  // x.r1<->y.r0, x.r3<->y.r2
}

__device__ __forceinline__ void gload16(const void* g, void* l) {
  // async global->LDS, 16B/lane; LDS dest = wave-uniform base + lane*16
  __builtin_amdgcn_global_load_lds(
      (__attribute__((address_space(1))) void*)g,
      (__attribute__((address_space(3))) void*)l, 16, 0, 0);
}

// ---------------- normalize rows of [rows][256] f32 -> bf16 ----------------
__global__ __launch_bounds__(256) void norm_kernel(const float* __restrict__ in,
                                                   u16* __restrict__ out, int rows) {
  const int wid = threadIdx.x >> 6, lane = threadIdx.x & 63;
  const int row = blockIdx.x * 4 + wid;
  if (row >= rows) return;
  const float4* p = (const float4*)(in + (size_t)row * NH);
  float4 v = p[lane];
  float ss = v.x * v.x + v.y * v.y + v.z * v.z + v.w * v.w;
#pragma unroll
  for (int m = 1; m <= 32; m <<= 1) ss += __shfl_xor(ss, m, 64);
  const float sc = 1.0f / fmaxf(sqrtf(ss), 1e-12f);  // matches F.normalize eps
  u16x4 o;
  o.x = f2bf(v.x * sc); o.y = f2bf(v.y * sc);
  o.z = f2bf(v.z * sc); o.w = f2bf(v.w * sc);
  *(u16x4*)(out + (size_t)row * NH + lane * 4) = o;
}

// ---- V [16384][28] f32 -> Vt [32][16384] bf16; col 28 = 1.0 (intensity) ---
__global__ __launch_bounds__(256) void vt_kernel(const float* __restrict__ V,
                                                 u16* __restrict__ Vt) {
  const int d = blockIdx.x * 256 + threadIdx.x;  // 16384
#pragma unroll
  for (int c = 0; c < NC; ++c) Vt[(size_t)c * ND + d] = f2bf(V[(size_t)d * NC + c]);
  Vt[(size_t)28 * ND + d] = 0x3F80;  // bf16 1.0 -> echo col 28 == intensity
  Vt[(size_t)29 * ND + d] = 0;
  Vt[(size_t)30 * ND + d] = 0;
  Vt[(size_t)31 * ND + d] = 0;
}

// ---------------- fused main kernel ----------------------------------------
// grid 1024: dch = bid&15 (XCD-local), ntile = bid>>4. 4 waves, 1x4 over q:
// wave w owns q-rows [ntile*128+w*32, +32) x 64 d-rows per tile.
// Q (all H) in registers. LDS 32KB = 2 bufs of [4 k2][64 d][64B] (16KB each).
// Sub-slab swizzle (R12-proven): stored chunk p at row R = logical p^((R>>1)&3).
__global__ __launch_bounds__(256, 4) void fused_kernel(
    const u16* __restrict__ Qn, const u16* __restrict__ Kn,
    const u16* __restrict__ Vt, float* __restrict__ ep) {
  __shared__ alignas(16) char smem[32768];
  const int tid = threadIdx.x;
  const int wid = tid >> 6;
  const int lane = tid & 63;
  const int l16 = lane & 15;
  const int lg = lane >> 4;
  const int dch = blockIdx.x & 15;
  const int ntile = blockIdx.x >> 4;
  const int rowbase = ntile * 128 + wid * 32;

  // ---- Q fragments, all H, in registers (MFMA B-operand) ----
  bf16x8 qA[2][8];
#pragma unroll
  for (int mb = 0; mb < 2; ++mb)
#pragma unroll
    for (int ks = 0; ks < 8; ++ks)
      qA[mb][ks] = *(const bf16x8*)(Qn + (size_t)(rowbase + mb * 16 + l16) * NH +
                                    ks * 32 + lg * 8);

  f32x4 eacc[2][2];
#pragma unroll
  for (int mb = 0; mb < 2; ++mb) {
    eacc[mb][0] = f32x4{0.f, 0.f, 0.f, 0.f};
    eacc[mb][1] = f32x4{0.f, 0.f, 0.f, 0.f};
  }
  f32x4 sacc[2][4];

  const u16* kc = Kn + (size_t)dch * DCHUNK * NH;
  // staging decomposition (thread tid stages, for each k2=r: row d, chunk c):
  //   d = (tid>>6)*16 + ((tid>>2)&15), stored chunk = tid&3,
  //   logical chunk = (tid&3) ^ ((d>>1)&3) = (tid&3) ^ ((tid>>3)&3)
  const int srow = (tid >> 6) * 16 + ((tid >> 2) & 15);
  const u16* kb = kc + (size_t)srow * NH + ((tid & 3) ^ ((tid >> 3) & 3)) * 8;

  // stage one [64d][128k] half-tile -> buf as 4 sub-slabs [64d][64B]
  auto stage = [&](int buf, const u16* src0) {
#pragma unroll
    for (int r = 0; r < 4; ++r)
      gload16(src0 + r * 32,
              smem + buf * 16384 + r * 4096 + wid * 1024);
  };

  const int rsw = (l16 >> 1) & 3;  // (row>>1)&3 for row = nb*16 + l16

  // compute one staged half h (buf): 4 k2-steps of 32k; B-frags in PAIRS
  // (live temps 8 regs instead of 16) (D = S^T, swapped operands)
  auto compute = [&](int buf, int h) {
    const char* kbuf = smem + buf * 16384;
#pragma unroll
    for (int k2 = 0; k2 < 4; ++k2) {
      const char* base = kbuf + k2 * 4096 + l16 * 64 + ((lg ^ rsw) << 4);
#pragma unroll
      for (int np = 0; np < 2; ++np) {
        const bf16x8 B0 = *(const bf16x8*)(base + (np * 2 + 0) * 1024);
        const bf16x8 B1 = *(const bf16x8*)(base + (np * 2 + 1) * 1024);
#pragma unroll
        for (int mb = 0; mb < 2; ++mb) {
          sacc[mb][np * 2 + 0] = __builtin_amdgcn_mfma_f32_16x16x32_bf16(
              B0, qA[mb][h * 4 + k2], sacc[mb][np * 2 + 0], 0, 0, 0);
          sacc[mb][np * 2 + 1] = __builtin_amdgcn_mfma_f32_16x16x32_bf16(
              B1, qA[mb][h * 4 + k2], sacc[mb][np * 2 + 1], 0, 0, 0);
        }
      }
    }
  };

  // prologue: tile 0 half 0 -> buf 0
  stage(0, kb);
  __syncthreads();

  for (int t = 0; t < NDT; ++t) {
    const size_t toff = (size_t)t * 64 * NH;
#pragma unroll
    for (int mb = 0; mb < 2; ++mb)
#pragma unroll
      for (int nb = 0; nb < 4; ++nb) sacc[mb][nb] = f32x4{0.f, 0.f, 0.f, 0.f};

    // s0: stage half1 -> buf1, compute half0 (buf0)
    stage(1, kb + toff + 128);
    compute(0, 0);
    __syncthreads();
    // s1: stage next tile half0 -> buf0, compute half1 (buf1)
    if (t < NDT - 1) stage(0, kb + toff + 64 * NH);
    compute(1, 1);
    __syncthreads();

    // ---- cube (fp32) -> bf16 pack -> permlane transpose -> PV MFMA ----
    // sacc[mb][nb]: q = l16, d(in tile) = nb*16 + lg*4 + r.
    const int dbase = dch * DCHUNK + t * 64;
#pragma unroll
    for (int mb = 0; mb < 2; ++mb) {
#pragma unroll
      for (int tg = 0; tg < 2; ++tg) {
        f32x4 sx = sacc[mb][2 * tg];
        f32x4 sy = sacc[mb][2 * tg + 1];
        f32x4 cx = sx * sx * sx;
        f32x4 cy = sy * sy * sy;
        unsigned x0 = cvtpk(cx[0], cx[1]);  // d = 4lg+0,1   (nb = 2tg)
        unsigned x1 = cvtpk(cx[2], cx[3]);  // d = 4lg+2,3
        unsigned y0 = cvtpk(cy[0], cy[1]);  // same, nb = 2tg+1
        unsigned y1 = cvtpk(cy[2], cy[3]);
        swap2(x0, y0);  // x0 -> a0 (k 8g+0,1), y0 -> a2 (k 8g+4,5)
        swap2(x1, y1);  // x1 -> a1 (k 8g+2,3), y1 -> a3 (k 8g+6,7)
        const int4 ai = {(int)x0, (int)x1, (int)y0, (int)y1};
        const bf16x8 aA = __builtin_bit_cast(bf16x8, ai);
#pragma unroll
        for (int cn = 0; cn < 2; ++cn) {
          const bf16x8 vBf = *(const bf16x8*)(Vt + (size_t)(cn * 16 + l16) * ND +
                                              dbase + tg * 32 + lg * 8);
          eacc[mb][cn] = __builtin_amdgcn_mfma_f32_16x16x32_bf16(
              aA, vBf, eacc[mb][cn], 0, 0, 0);
        }
      }
    }
    // PV touches no LDS; buffers protected by the s0/s1 barriers.
  }

  // ---- epilogue: write partials (slot = dch) ----
#pragma unroll
  for (int mb = 0; mb < 2; ++mb)
#pragma unroll
    for (int cn = 0; cn < 2; ++cn)
#pragma unroll
      for (int r = 0; r < 4; ++r) {
        const int row = rowbase + mb * 16 + lg * 4 + r;
        ep[((size_t)dch * NQ + row) * 32 + cn * 16 + l16] = eacc[mb][cn][r];
      }
}

// ---------------- reduce 16 partial slots -> d_out -------------------------
__global__ __launch_bounds__(256) void reduce_kernel(const float* __restrict__ ep,
                                                     float* __restrict__ out) {
  const int g = blockIdx.x * 256 + threadIdx.x;  // 8192*32
  const int q = g >> 5, c = g & 31;
  if (c < NC) {
    float s = 0.f;
#pragma unroll
    for (int k = 0; k < NSLOT; ++k) s += ep[((size_t)k * NQ + q) * 32 + c];
    out[(size_t)q * NC + c] = s;
  } else if (c == NC) {  // ones-column == intensity
    float s = 0.f;
#pragma unroll
    for (int k = 0; k < NSLOT; ++k) s += ep[((size_t)k * NQ + q) * 32 + NC];
    out[(size_t)NQ * NC + q] = s;
  }
}

extern "C" void kernel_launch(void* const* d_in, const int* in_sizes, int n_in,
                              void* d_out, int out_size, void* d_ws, size_t ws_size,
                              hipStream_t stream) {
  const float* feat = (const float*)d_in[0];  // [8192][256]
  const float* exf  = (const float*)d_in[1];  // [16384][256]
  const float* exc  = (const float*)d_in[2];  // [16384][28]
  float* out = (float*)d_out;
  char* ws = (char*)d_ws;
  // ws layout: qn 4MB | kn 8MB | vt 1MB | ep 16MB  (~29MB)
  u16* qn = (u16*)ws;
  u16* kn = (u16*)(ws + 4194304);
  u16* vt = (u16*)(ws + 12582912);
  float* ep = (float*)(ws + 13631488);

  norm_kernel<<<dim3(NQ / 4), dim3(256), 0, stream>>>(feat, qn, NQ);
  norm_kernel<<<dim3(ND / 4), dim3(256), 0, stream>>>(exf, kn, ND);
  vt_kernel<<<dim3(ND / 256), dim3(256), 0, stream>>>(exc, vt);
  fused_kernel<<<dim3(1024), dim3(256), 0, stream>>>(qn, kn, vt, ep);
  reduce_kernel<<<dim3(NQ * 32 / 256), dim3(256), 0, stream>>>(ep, out);
}

// Round 16
// 95.227 us; speedup vs baseline: 1.0946x; 1.0946x over previous
//
#include <hip/hip_runtime.h>
#include <stdint.h>

// minerva2: echo = (F̂ Ê^T)^3 @ V, intensity = rowsum((F̂ Ê^T)^3)
// R16 = R14 (best: 64-row D-tiles, R12-proven zero-conflict sub-slab layout,
// Q resident, swapped QK^T + in-reg cube/cvt_pk/permlane -> PV) +
//   NSLOT 8 (half ep traffic, grid 512, perfect XCD/K-chunk affinity) +
//   T5 setprio around QK MFMA cluster.

typedef unsigned short u16;
typedef __bf16 bf16x8 __attribute__((ext_vector_type(8)));
typedef float f32x4 __attribute__((ext_vector_type(4)));
typedef unsigned short u16x4 __attribute__((ext_vector_type(4)));

#define NQ 8192
#define ND 16384
#define NH 256
#define NC 28
#define DCHUNK 2048
#define NDT 32       // 64-row D-tiles per chunk
#define NSLOT 8      // partial slots = 8 D-chunks (one per XCD)

__device__ __forceinline__ u16 f2bf(float f) {
  unsigned u = __builtin_bit_cast(unsigned, f);
  u += 0x7fffu + ((u >> 16) & 1u);   // RNE
  return (u16)(u >> 16);
}

__device__ __forceinline__ unsigned cvtpk(float lo, float hi) {
  unsigned r;
  asm("v_cvt_pk_bf16_f32 %0, %1, %2" : "=v"(r) : "v"(lo), "v"(hi));
  return r;  // low16 = bf16(lo), high16 = bf16(hi)  (RNE)
}

// After: x = [x.r0, x.r2, y.r0, y.r2] (by 16-lane row), y = [x.r1, x.r3, y.r1, y.r3]
__device__ __forceinline__ void swap2(unsigned& x, unsigned& y) {
  asm("v_permlane32_swap_b32 %0, %1" : "+v"(x), "+v"(y));  // x.r23 <-> y.r01
  asm("v_permlane16_swap_b32 %0, %1" : "+v"(x), "+v"(y));  // x.r1<->y.r0, x.r3<->y.r2
}

__device__ __forceinline__ void gload16(const void* g, void* l) {
  // async global->LDS, 16B/lane; LDS dest = wave-uniform base + lane*16
  __builtin_amdgcn_global_load_lds(
      (__attribute__((address_space(1))) void*)g,
      (__attribute__((address_space(3))) void*)l, 16, 0, 0);
}

// ---------------- normalize rows of [rows][256] f32 -> bf16 ----------------
__global__ __launch_bounds__(256) void norm_kernel(const float* __restrict__ in,
                                                   u16* __restrict__ out, int rows) {
  const int wid = threadIdx.x >> 6, lane = threadIdx.x & 63;
  const int row = blockIdx.x * 4 + wid;
  if (row >= rows) return;
  const float4* p = (const float4*)(in + (size_t)row * NH);
  float4 v = p[lane];
  float ss = v.x * v.x + v.y * v.y + v.z * v.z + v.w * v.w;
#pragma unroll
  for (int m = 1; m <= 32; m <<= 1) ss += __shfl_xor(ss, m, 64);
  const float sc = 1.0f / fmaxf(sqrtf(ss), 1e-12f);  // matches F.normalize eps
  u16x4 o;
  o.x = f2bf(v.x * sc); o.y = f2bf(v.y * sc);
  o.z = f2bf(v.z * sc); o.w = f2bf(v.w * sc);
  *(u16x4*)(out + (size_t)row * NH + lane * 4) = o;
}

// ---- V [16384][28] f32 -> Vt [32][16384] bf16; col 28 = 1.0 (intensity) ---
__global__ __launch_bounds__(256) void vt_kernel(const float* __restrict__ V,
                                                 u16* __restrict__ Vt) {
  const int d = blockIdx.x * 256 + threadIdx.x;  // 16384
#pragma unroll
  for (int c = 0; c < NC; ++c) Vt[(size_t)c * ND + d] = f2bf(V[(size_t)d * NC + c]);
  Vt[(size_t)28 * ND + d] = 0x3F80;  // bf16 1.0 -> echo col 28 == intensity
  Vt[(size_t)29 * ND + d] = 0;
  Vt[(size_t)30 * ND + d] = 0;
  Vt[(size_t)31 * ND + d] = 0;
}

// ---------------- fused main kernel ----------------------------------------
// grid 512: dch = bid&7 (one 2MB K-chunk per XCD, L2-resident), ntile = bid>>3.
// 4 waves, 1x4 over q: wave w owns q-rows [ntile*128+w*32, +32) x 64 d/tile.
// Q (all H) in registers. LDS 32KB = 2 bufs of [4 k2][64 d][64B] (16KB each).
// Sub-slab swizzle (R12-proven): stored chunk p at row R = logical p^((R>>1)&3).
__global__ __launch_bounds__(256, 3) void fused_kernel(
    const u16* __restrict__ Qn, const u16* __restrict__ Kn,
    const u16* __restrict__ Vt, float* __restrict__ ep) {
  __shared__ alignas(16) char smem[32768];
  const int tid = threadIdx.x;
  const int wid = tid >> 6;
  const int lane = tid & 63;
  const int l16 = lane & 15;
  const int lg = lane >> 4;
  const int dch = blockIdx.x & 7;
  const int ntile = blockIdx.x >> 3;
  const int rowbase = ntile * 128 + wid * 32;

  // ---- Q fragments, all H, in registers (MFMA B-operand) ----
  bf16x8 qA[2][8];
#pragma unroll
  for (int mb = 0; mb < 2; ++mb)
#pragma unroll
    for (int ks = 0; ks < 8; ++ks)
      qA[mb][ks] = *(const bf16x8*)(Qn + (size_t)(rowbase + mb * 16 + l16) * NH +
                                    ks * 32 + lg * 8);

  f32x4 eacc[2][2];
#pragma unroll
  for (int mb = 0; mb < 2; ++mb) {
    eacc[mb][0] = f32x4{0.f, 0.f, 0.f, 0.f};
    eacc[mb][1] = f32x4{0.f, 0.f, 0.f, 0.f};
  }
  f32x4 sacc[2][4];

  const u16* kc = Kn + (size_t)dch * DCHUNK * NH;
  // staging decomposition (thread tid stages, for each k2=r: row d, chunk c):
  //   d = (tid>>6)*16 + ((tid>>2)&15), stored chunk = tid&3,
  //   logical chunk = (tid&3) ^ ((d>>1)&3) = (tid&3) ^ ((tid>>3)&3)
  const int srow = (tid >> 6) * 16 + ((tid >> 2) & 15);
  const u16* kb = kc + (size_t)srow * NH + ((tid & 3) ^ ((tid >> 3) & 3)) * 8;

  // stage one [64d][128k] half-tile -> buf as 4 sub-slabs [64d][64B]
  auto stage = [&](int buf, const u16* src0) {
#pragma unroll
    for (int r = 0; r < 4; ++r)
      gload16(src0 + r * 32,
              smem + buf * 16384 + r * 4096 + wid * 1024);
  };

  const int rsw = (l16 >> 1) & 3;  // (row>>1)&3 for row = nb*16 + l16

  // compute one staged half h (buf): 4 k2-steps of 32k, 8 MFMA each (D = S^T)
  auto compute = [&](int buf, int h) {
    const char* kbuf = smem + buf * 16384;
#pragma unroll
    for (int k2 = 0; k2 < 4; ++k2) {
      bf16x8 B[4];
#pragma unroll
      for (int nb = 0; nb < 4; ++nb)
        B[nb] = *(const bf16x8*)(kbuf + k2 * 4096 + (nb * 16 + l16) * 64 +
                                 ((lg ^ rsw) << 4));
      __builtin_amdgcn_s_setprio(1);
#pragma unroll
      for (int mb = 0; mb < 2; ++mb)
#pragma unroll
        for (int nb = 0; nb < 4; ++nb)
          sacc[mb][nb] = __builtin_amdgcn_mfma_f32_16x16x32_bf16(
              B[nb], qA[mb][h * 4 + k2], sacc[mb][nb], 0, 0, 0);
      __builtin_amdgcn_s_setprio(0);
    }
  };

  // prologue: tile 0 half 0 -> buf 0
  stage(0, kb);
  __syncthreads();

  for (int t = 0; t < NDT; ++t) {
    const size_t toff = (size_t)t * 64 * NH;
#pragma unroll
    for (int mb = 0; mb < 2; ++mb)
#pragma unroll
      for (int nb = 0; nb < 4; ++nb) sacc[mb][nb] = f32x4{0.f, 0.f, 0.f, 0.f};

    // s0: stage half1 -> buf1, compute half0 (buf0)
    stage(1, kb + toff + 128);
    compute(0, 0);
    __syncthreads();
    // s1: stage next tile half0 -> buf0, compute half1 (buf1)
    if (t < NDT - 1) stage(0, kb + toff + 64 * NH);
    compute(1, 1);
    __syncthreads();

    // ---- cube (fp32) -> bf16 pack -> permlane transpose -> PV MFMA ----
    // sacc[mb][nb]: q = l16, d(in tile) = nb*16 + lg*4 + r.
    const int dbase = dch * DCHUNK + t * 64;
#pragma unroll
    for (int mb = 0; mb < 2; ++mb) {
#pragma unroll
      for (int tg = 0; tg < 2; ++tg) {
        f32x4 sx = sacc[mb][2 * tg];
        f32x4 sy = sacc[mb][2 * tg + 1];
        f32x4 cx = sx * sx * sx;
        f32x4 cy = sy * sy * sy;
        unsigned x0 = cvtpk(cx[0], cx[1]);  // d = 4lg+0,1   (nb = 2tg)
        unsigned x1 = cvtpk(cx[2], cx[3]);  // d = 4lg+2,3
        unsigned y0 = cvtpk(cy[0], cy[1]);  // same, nb = 2tg+1
        unsigned y1 = cvtpk(cy[2], cy[3]);
        swap2(x0, y0);  // x0 -> a0 (k 8g+0,1), y0 -> a2 (k 8g+4,5)
        swap2(x1, y1);  // x1 -> a1 (k 8g+2,3), y1 -> a3 (k 8g+6,7)
        const int4 ai = {(int)x0, (int)x1, (int)y0, (int)y1};
        const bf16x8 aA = __builtin_bit_cast(bf16x8, ai);
#pragma unroll
        for (int cn = 0; cn < 2; ++cn) {
          const bf16x8 vBf = *(const bf16x8*)(Vt + (size_t)(cn * 16 + l16) * ND +
                                              dbase + tg * 32 + lg * 8);
          eacc[mb][cn] = __builtin_amdgcn_mfma_f32_16x16x32_bf16(
              aA, vBf, eacc[mb][cn], 0, 0, 0);
        }
      }
    }
    // PV touches no LDS; buffers protected by the s0/s1 barriers.
  }

  // ---- epilogue: write partials (slot = dch) ----
#pragma unroll
  for (int mb = 0; mb < 2; ++mb)
#pragma unroll
    for (int cn = 0; cn < 2; ++cn)
#pragma unroll
      for (int r = 0; r < 4; ++r) {
        const int row = rowbase + mb * 16 + lg * 4 + r;
        ep[((size_t)dch * NQ + row) * 32 + cn * 16 + l16] = eacc[mb][cn][r];
      }
}

// ---------------- reduce 8 partial slots -> d_out --------------------------
__global__ __launch_bounds__(256) void reduce_kernel(const float* __restrict__ ep,
                                                     float* __restrict__ out) {
  const int g = blockIdx.x * 256 + threadIdx.x;  // 8192*32
  const int q = g >> 5, c = g & 31;
  if (c < NC) {
    float s = 0.f;
#pragma unroll
    for (int k = 0; k < NSLOT; ++k) s += ep[((size_t)k * NQ + q) * 32 + c];
    out[(size_t)q * NC + c] = s;
  } else if (c == NC) {  // ones-column == intensity
    float s = 0.f;
#pragma unroll
    for (int k = 0; k < NSLOT; ++k) s += ep[((size_t)k * NQ + q) * 32 + NC];
    out[(size_t)NQ * NC + q] = s;
  }
}

extern "C" void kernel_launch(void* const* d_in, const int* in_sizes, int n_in,
                              void* d_out, int out_size, void* d_ws, size_t ws_size,
                              hipStream_t stream) {
  const float* feat = (const float*)d_in[0];  // [8192][256]
  const float* exf  = (const float*)d_in[1];  // [16384][256]
  const float* exc  = (const float*)d_in[2];  // [16384][28]
  float* out = (float*)d_out;
  char* ws = (char*)d_ws;
  // ws layout: qn 4MB | kn 8MB | vt 1MB | ep 8MB  (~21MB)
  u16* qn = (u16*)ws;
  u16* kn = (u16*)(ws + 4194304);
  u16* vt = (u16*)(ws + 12582912);
  float* ep = (float*)(ws + 13631488);

  norm_kernel<<<dim3(NQ / 4), dim3(256), 0, stream>>>(feat, qn, NQ);
  norm_kernel<<<dim3(ND / 4), dim3(256), 0, stream>>>(exf, kn, ND);
  vt_kernel<<<dim3(ND / 256), dim3(256), 0, stream>>>(exc, vt);
  fused_kernel<<<dim3(512), dim3(256), 0, stream>>>(qn, kn, vt, ep);
  reduce_kernel<<<dim3(NQ * 32 / 256), dim3(256), 0, stream>>>(ep, out);
}

// Round 17
// 86.853 us; speedup vs baseline: 1.2002x; 1.0964x over previous
//
#include <hip/hip_runtime.h>
#include <stdint.h>

// minerva2: echo = (F̂ Ê^T)^3 @ V, intensity = rowsum((F̂ Ê^T)^3)
// R17 = R16 (best) + prep-kernel fusion (norm(feat)+norm(exf)+vt in one
// launch) + Vt B-frag hoist to tile start (PV becomes load-free; latency
// drains under the existing s0 barrier).

typedef unsigned short u16;
typedef __bf16 bf16x8 __attribute__((ext_vector_type(8)));
typedef float f32x4 __attribute__((ext_vector_type(4)));
typedef unsigned short u16x4 __attribute__((ext_vector_type(4)));

#define NQ 8192
#define ND 16384
#define NH 256
#define NC 28
#define DCHUNK 2048
#define NDT 32       // 64-row D-tiles per chunk
#define NSLOT 8      // partial slots = 8 D-chunks (one per XCD)

__device__ __forceinline__ u16 f2bf(float f) {
  unsigned u = __builtin_bit_cast(unsigned, f);
  u += 0x7fffu + ((u >> 16) & 1u);   // RNE
  return (u16)(u >> 16);
}

__device__ __forceinline__ unsigned cvtpk(float lo, float hi) {
  unsigned r;
  asm("v_cvt_pk_bf16_f32 %0, %1, %2" : "=v"(r) : "v"(lo), "v"(hi));
  return r;  // low16 = bf16(lo), high16 = bf16(hi)  (RNE)
}

// After: x = [x.r0, x.r2, y.r0, y.r2] (by 16-lane row), y = [x.r1, x.r3, y.r1, y.r3]
__device__ __forceinline__ void swap2(unsigned& x, unsigned& y) {
  asm("v_permlane32_swap_b32 %0, %1" : "+v"(x), "+v"(y));  // x.r23 <-> y.r01
  asm("v_permlane16_swap_b32 %0, %1" : "+v"(x), "+v"(y));  // x.r1<->y.r0, x.r3<->y.r2
}

__device__ __forceinline__ void gload16(const void* g, void* l) {
  // async global->LDS, 16B/lane; LDS dest = wave-uniform base + lane*16
  __builtin_amdgcn_global_load_lds(
      (__attribute__((address_space(1))) void*)g,
      (__attribute__((address_space(3))) void*)l, 16, 0, 0);
}

// ---- prep: rows 0..24575 = L2-normalize (feat->qn, exf->kn); then Vt ------
// grid 6208 x 256: blocks [0,6144) norm 4 rows each; [6144,6208) transpose V.
__global__ __launch_bounds__(256) void prep_kernel(
    const float* __restrict__ feat, const float* __restrict__ exf,
    const float* __restrict__ V, u16* __restrict__ qn, u16* __restrict__ kn,
    u16* __restrict__ Vt) {
  if (blockIdx.x < 6144) {
    const int wid = threadIdx.x >> 6, lane = threadIdx.x & 63;
    const int row = blockIdx.x * 4 + wid;
    const float* in = (row < NQ) ? feat + (size_t)row * NH
                                 : exf + (size_t)(row - NQ) * NH;
    u16* out = (row < NQ) ? qn + (size_t)row * NH : kn + (size_t)(row - NQ) * NH;
    float4 v = ((const float4*)in)[lane];
    float ss = v.x * v.x + v.y * v.y + v.z * v.z + v.w * v.w;
#pragma unroll
    for (int m = 1; m <= 32; m <<= 1) ss += __shfl_xor(ss, m, 64);
    const float sc = 1.0f / fmaxf(sqrtf(ss), 1e-12f);  // matches F.normalize eps
    u16x4 o;
    o.x = f2bf(v.x * sc); o.y = f2bf(v.y * sc);
    o.z = f2bf(v.z * sc); o.w = f2bf(v.w * sc);
    *(u16x4*)(out + lane * 4) = o;
  } else {
    const int d = (blockIdx.x - 6144) * 256 + threadIdx.x;  // 16384
#pragma unroll
    for (int c = 0; c < NC; ++c) Vt[(size_t)c * ND + d] = f2bf(V[(size_t)d * NC + c]);
    Vt[(size_t)28 * ND + d] = 0x3F80;  // bf16 1.0 -> echo col 28 == intensity
    Vt[(size_t)29 * ND + d] = 0;
    Vt[(size_t)30 * ND + d] = 0;
    Vt[(size_t)31 * ND + d] = 0;
  }
}

// ---------------- fused main kernel ----------------------------------------
// grid 512: dch = bid&7 (one 2MB K-chunk per XCD, L2-resident), ntile = bid>>3.
// 4 waves, 1x4 over q: wave w owns q-rows [ntile*128+w*32, +32) x 64 d/tile.
// Q (all H) in registers. LDS 32KB = 2 bufs of [4 k2][64 d][64B] (16KB each).
// Sub-slab swizzle (R12-proven): stored chunk p at row R = logical p^((R>>1)&3).
__global__ __launch_bounds__(256, 3) void fused_kernel(
    const u16* __restrict__ Qn, const u16* __restrict__ Kn,
    const u16* __restrict__ Vt, float* __restrict__ ep) {
  __shared__ alignas(16) char smem[32768];
  const int tid = threadIdx.x;
  const int wid = tid >> 6;
  const int lane = tid & 63;
  const int l16 = lane & 15;
  const int lg = lane >> 4;
  const int dch = blockIdx.x & 7;
  const int ntile = blockIdx.x >> 3;
  const int rowbase = ntile * 128 + wid * 32;

  // ---- Q fragments, all H, in registers (MFMA B-operand) ----
  bf16x8 qA[2][8];
#pragma unroll
  for (int mb = 0; mb < 2; ++mb)
#pragma unroll
    for (int ks = 0; ks < 8; ++ks)
      qA[mb][ks] = *(const bf16x8*)(Qn + (size_t)(rowbase + mb * 16 + l16) * NH +
                                    ks * 32 + lg * 8);

  f32x4 eacc[2][2];
#pragma unroll
  for (int mb = 0; mb < 2; ++mb) {
    eacc[mb][0] = f32x4{0.f, 0.f, 0.f, 0.f};
    eacc[mb][1] = f32x4{0.f, 0.f, 0.f, 0.f};
  }
  f32x4 sacc[2][4];

  const u16* kc = Kn + (size_t)dch * DCHUNK * NH;
  // staging decomposition (thread tid stages, for each k2=r: row d, chunk c):
  //   d = (tid>>6)*16 + ((tid>>2)&15), stored chunk = tid&3,
  //   logical chunk = (tid&3) ^ ((d>>1)&3) = (tid&3) ^ ((tid>>3)&3)
  const int srow = (tid >> 6) * 16 + ((tid >> 2) & 15);
  const u16* kb = kc + (size_t)srow * NH + ((tid & 3) ^ ((tid >> 3) & 3)) * 8;

  // stage one [64d][128k] half-tile -> buf as 4 sub-slabs [64d][64B]
  auto stage = [&](int buf, const u16* src0) {
#pragma unroll
    for (int r = 0; r < 4; ++r)
      gload16(src0 + r * 32,
              smem + buf * 16384 + r * 4096 + wid * 1024);
  };

  const int rsw = (l16 >> 1) & 3;  // (row>>1)&3 for row = nb*16 + l16

  // compute one staged half h (buf): 4 k2-steps of 32k, 8 MFMA each (D = S^T)
  auto compute = [&](int buf, int h) {
    const char* kbuf = smem + buf * 16384;
#pragma unroll
    for (int k2 = 0; k2 < 4; ++k2) {
      bf16x8 B[4];
#pragma unroll
      for (int nb = 0; nb < 4; ++nb)
        B[nb] = *(const bf16x8*)(kbuf + k2 * 4096 + (nb * 16 + l16) * 64 +
                                 ((lg ^ rsw) << 4));
      __builtin_amdgcn_s_setprio(1);
#pragma unroll
      for (int mb = 0; mb < 2; ++mb)
#pragma unroll
        for (int nb = 0; nb < 4; ++nb)
          sacc[mb][nb] = __builtin_amdgcn_mfma_f32_16x16x32_bf16(
              B[nb], qA[mb][h * 4 + k2], sacc[mb][nb], 0, 0, 0);
      __builtin_amdgcn_s_setprio(0);
    }
  };

  // prologue: tile 0 half 0 -> buf 0
  stage(0, kb);
  __syncthreads();

  for (int t = 0; t < NDT; ++t) {
    const size_t toff = (size_t)t * 64 * NH;
    const int dbase = dch * DCHUNK + t * 64;

    // hoisted Vt B-frags for this tile's PV (drain under s0's barrier)
    bf16x8 vB[2][2];
#pragma unroll
    for (int tg = 0; tg < 2; ++tg)
#pragma unroll
      for (int cn = 0; cn < 2; ++cn)
        vB[tg][cn] = *(const bf16x8*)(Vt + (size_t)(cn * 16 + l16) * ND +
                                      dbase + tg * 32 + lg * 8);

#pragma unroll
    for (int mb = 0; mb < 2; ++mb)
#pragma unroll
      for (int nb = 0; nb < 4; ++nb) sacc[mb][nb] = f32x4{0.f, 0.f, 0.f, 0.f};

    // s0: stage half1 -> buf1, compute half0 (buf0)
    stage(1, kb + toff + 128);
    compute(0, 0);
    __syncthreads();
    // s1: stage next tile half0 -> buf0, compute half1 (buf1)
    if (t < NDT - 1) stage(0, kb + toff + 64 * NH);
    compute(1, 1);
    __syncthreads();

    // ---- cube (fp32) -> bf16 pack -> permlane transpose -> PV MFMA ----
    // sacc[mb][nb]: q = l16, d(in tile) = nb*16 + lg*4 + r.
#pragma unroll
    for (int mb = 0; mb < 2; ++mb) {
#pragma unroll
      for (int tg = 0; tg < 2; ++tg) {
        f32x4 sx = sacc[mb][2 * tg];
        f32x4 sy = sacc[mb][2 * tg + 1];
        f32x4 cx = sx * sx * sx;
        f32x4 cy = sy * sy * sy;
        unsigned x0 = cvtpk(cx[0], cx[1]);  // d = 4lg+0,1   (nb = 2tg)
        unsigned x1 = cvtpk(cx[2], cx[3]);  // d = 4lg+2,3
        unsigned y0 = cvtpk(cy[0], cy[1]);  // same, nb = 2tg+1
        unsigned y1 = cvtpk(cy[2], cy[3]);
        swap2(x0, y0);  // x0 -> a0 (k 8g+0,1), y0 -> a2 (k 8g+4,5)
        swap2(x1, y1);  // x1 -> a1 (k 8g+2,3), y1 -> a3 (k 8g+6,7)
        const int4 ai = {(int)x0, (int)x1, (int)y0, (int)y1};
        const bf16x8 aA = __builtin_bit_cast(bf16x8, ai);
#pragma unroll
        for (int cn = 0; cn < 2; ++cn)
          eacc[mb][cn] = __builtin_amdgcn_mfma_f32_16x16x32_bf16(
              aA, vB[tg][cn], eacc[mb][cn], 0, 0, 0);
      }
    }
    // PV touches no LDS/global; buffers protected by the s0/s1 barriers.
  }

  // ---- epilogue: write partials (slot = dch) ----
#pragma unroll
  for (int mb = 0; mb < 2; ++mb)
#pragma unroll
    for (int cn = 0; cn < 2; ++cn)
#pragma unroll
      for (int r = 0; r < 4; ++r) {
        const int row = rowbase + mb * 16 + lg * 4 + r;
        ep[((size_t)dch * NQ + row) * 32 + cn * 16 + l16] = eacc[mb][cn][r];
      }
}

// ---------------- reduce 8 partial slots -> d_out --------------------------
__global__ __launch_bounds__(256) void reduce_kernel(const float* __restrict__ ep,
                                                     float* __restrict__ out) {
  const int g = blockIdx.x * 256 + threadIdx.x;  // 8192*32
  const int q = g >> 5, c = g & 31;
  if (c < NC) {
    float s = 0.f;
#pragma unroll
    for (int k = 0; k < NSLOT; ++k) s += ep[((size_t)k * NQ + q) * 32 + c];
    out[(size_t)q * NC + c] = s;
  } else if (c == NC) {  // ones-column == intensity
    float s = 0.f;
#pragma unroll
    for (int k = 0; k < NSLOT; ++k) s += ep[((size_t)k * NQ + q) * 32 + NC];
    out[(size_t)NQ * NC + q] = s;
  }
}

extern "C" void kernel_launch(void* const* d_in, const int* in_sizes, int n_in,
                              void* d_out, int out_size, void* d_ws, size_t ws_size,
                              hipStream_t stream) {
  const float* feat = (const float*)d_in[0];  // [8192][256]
  const float* exf  = (const float*)d_in[1];  // [16384][256]
  const float* exc  = (const float*)d_in[2];  // [16384][28]
  float* out = (float*)d_out;
  char* ws = (char*)d_ws;
  // ws layout: qn 4MB | kn 8MB | vt 1MB | ep 8MB  (~21MB)
  u16* qn = (u16*)ws;
  u16* kn = (u16*)(ws + 4194304);
  u16* vt = (u16*)(ws + 12582912);
  float* ep = (float*)(ws + 13631488);

  prep_kernel<<<dim3(6208), dim3(256), 0, stream>>>(feat, exf, exc, qn, kn, vt);
  fused_kernel<<<dim3(512), dim3(256), 0, stream>>>(qn, kn, vt, ep);
  reduce_kernel<<<dim3(NQ * 32 / 256), dim3(256), 0, stream>>>(ep, out);
}

// Round 18
// 82.915 us; speedup vs baseline: 1.2572x; 1.0475x over previous
//
#include <hip/hip_runtime.h>
#include <stdint.h>

// minerva2: echo = (F̂ Ê^T)^3 @ V, intensity = rowsum((F̂ Ê^T)^3)
// R18 = R17 + 2x2 wave grid (wr = q-half, wd = d-half): wave owns 64q x 32d
// per tile -> LDS B-frag reads halved (2x dup instead of 4x). qA[4][8] full-H
// resident (128 VGPR); sacc[4][2]; eacc[4][2]; wd-merged epilogue (NSLOT=8).

typedef unsigned short u16;
typedef __bf16 bf16x8 __attribute__((ext_vector_type(8)));
typedef float f32x4 __attribute__((ext_vector_type(4)));
typedef unsigned short u16x4 __attribute__((ext_vector_type(4)));

#define NQ 8192
#define ND 16384
#define NH 256
#define NC 28
#define DCHUNK 2048
#define NDT 32       // 64-row D-tiles per chunk
#define NSLOT 8      // partial slots = 8 D-chunks (one per XCD; wd merged)

__device__ __forceinline__ u16 f2bf(float f) {
  unsigned u = __builtin_bit_cast(unsigned, f);
  u += 0x7fffu + ((u >> 16) & 1u);   // RNE
  return (u16)(u >> 16);
}

__device__ __forceinline__ unsigned cvtpk(float lo, float hi) {
  unsigned r;
  asm("v_cvt_pk_bf16_f32 %0, %1, %2" : "=v"(r) : "v"(lo), "v"(hi));
  return r;  // low16 = bf16(lo), high16 = bf16(hi)  (RNE)
}

// After: x = [x.r0, x.r2, y.r0, y.r2] (by 16-lane row), y = [x.r1, x.r3, y.r1, y.r3]
__device__ __forceinline__ void swap2(unsigned& x, unsigned& y) {
  asm("v_permlane32_swap_b32 %0, %1" : "+v"(x), "+v"(y));  // x.r23 <-> y.r01
  asm("v_permlane16_swap_b32 %0, %1" : "+v"(x), "+v"(y));  // x.r1<->y.r0, x.r3<->y.r2
}

__device__ __forceinline__ void gload16(const void* g, void* l) {
  // async global->LDS, 16B/lane; LDS dest = wave-uniform base + lane*16
  __builtin_amdgcn_global_load_lds(
      (__attribute__((address_space(1))) void*)g,
      (__attribute__((address_space(3))) void*)l, 16, 0, 0);
}

// ---- prep: rows 0..24575 = L2-normalize (feat->qn, exf->kn); then Vt ------
__global__ __launch_bounds__(256) void prep_kernel(
    const float* __restrict__ feat, const float* __restrict__ exf,
    const float* __restrict__ V, u16* __restrict__ qn, u16* __restrict__ kn,
    u16* __restrict__ Vt) {
  if (blockIdx.x < 6144) {
    const int wid = threadIdx.x >> 6, lane = threadIdx.x & 63;
    const int row = blockIdx.x * 4 + wid;
    const float* in = (row < NQ) ? feat + (size_t)row * NH
                                 : exf + (size_t)(row - NQ) * NH;
    u16* out = (row < NQ) ? qn + (size_t)row * NH : kn + (size_t)(row - NQ) * NH;
    float4 v = ((const float4*)in)[lane];
    float ss = v.x * v.x + v.y * v.y + v.z * v.z + v.w * v.w;
#pragma unroll
    for (int m = 1; m <= 32; m <<= 1) ss += __shfl_xor(ss, m, 64);
    const float sc = 1.0f / fmaxf(sqrtf(ss), 1e-12f);  // matches F.normalize eps
    u16x4 o;
    o.x = f2bf(v.x * sc); o.y = f2bf(v.y * sc);
    o.z = f2bf(v.z * sc); o.w = f2bf(v.w * sc);
    *(u16x4*)(out + lane * 4) = o;
  } else {
    const int d = (blockIdx.x - 6144) * 256 + threadIdx.x;  // 16384
#pragma unroll
    for (int c = 0; c < NC; ++c) Vt[(size_t)c * ND + d] = f2bf(V[(size_t)d * NC + c]);
    Vt[(size_t)28 * ND + d] = 0x3F80;  // bf16 1.0 -> echo col 28 == intensity
    Vt[(size_t)29 * ND + d] = 0;
    Vt[(size_t)30 * ND + d] = 0;
    Vt[(size_t)31 * ND + d] = 0;
  }
}

// ---------------- fused main kernel ----------------------------------------
// grid 512: dch = bid&7 (one 2MB K-chunk per XCD, L2-resident), ntile = bid>>3.
// 4 waves, 2x2: wave (wr, wd) owns q-rows [ntile*128+wr*64, +64) x
// d-rows [wd*32, +32) of each 64-row D-tile.
// Q (all H) in registers (128 VGPR). LDS 32KB = 2 bufs [4 k2][64 d][64B].
// Sub-slab swizzle (R12-proven): stored chunk p at row R = logical p^((R>>1)&3).
__global__ __launch_bounds__(256, 2) void fused_kernel(
    const u16* __restrict__ Qn, const u16* __restrict__ Kn,
    const u16* __restrict__ Vt, float* __restrict__ ep) {
  __shared__ alignas(16) char smem[32768];
  const int tid = threadIdx.x;
  const int wid = tid >> 6;
  const int lane = tid & 63;
  const int l16 = lane & 15;
  const int lg = lane >> 4;
  const int wr = wid >> 1;
  const int wd = wid & 1;
  const int dch = blockIdx.x & 7;
  const int ntile = blockIdx.x >> 3;
  const int rowbase = ntile * 128 + wr * 64;

  // ---- Q fragments, 64 rows x all H, in registers (MFMA B-operand) ----
  bf16x8 qA[4][8];
#pragma unroll
  for (int mb = 0; mb < 4; ++mb)
#pragma unroll
    for (int ks = 0; ks < 8; ++ks)
      qA[mb][ks] = *(const bf16x8*)(Qn + (size_t)(rowbase + mb * 16 + l16) * NH +
                                    ks * 32 + lg * 8);

  f32x4 eacc[4][2];
#pragma unroll
  for (int mb = 0; mb < 4; ++mb) {
    eacc[mb][0] = f32x4{0.f, 0.f, 0.f, 0.f};
    eacc[mb][1] = f32x4{0.f, 0.f, 0.f, 0.f};
  }
  f32x4 sacc[4][2];

  const u16* kc = Kn + (size_t)dch * DCHUNK * NH;
  // staging decomposition (unchanged): d = (tid>>6)*16 + ((tid>>2)&15),
  // stored chunk = tid&3, logical chunk = (tid&3) ^ ((tid>>3)&3)
  const int srow = (tid >> 6) * 16 + ((tid >> 2) & 15);
  const u16* kb = kc + (size_t)srow * NH + ((tid & 3) ^ ((tid >> 3) & 3)) * 8;

  // stage one [64d][128k] half-tile -> buf as 4 sub-slabs [64d][64B]
  auto stage = [&](int buf, const u16* src0) {
#pragma unroll
    for (int r = 0; r < 4; ++r)
      gload16(src0 + r * 32,
              smem + buf * 16384 + r * 4096 + wid * 1024);
  };

  const int rsw = (l16 >> 1) & 3;  // (row>>1)&3 for row = wd*32 + nb*16 + l16

  // compute one staged half h (buf): wave reads only its wd 32-d slice
  auto compute = [&](int buf, int h) {
    const char* kbuf = smem + buf * 16384;
#pragma unroll
    for (int k2 = 0; k2 < 4; ++k2) {
      bf16x8 B[2];
#pragma unroll
      for (int nb = 0; nb < 2; ++nb)
        B[nb] = *(const bf16x8*)(kbuf + k2 * 4096 + (wd * 32 + nb * 16 + l16) * 64 +
                                 ((lg ^ rsw) << 4));
      __builtin_amdgcn_s_setprio(1);
#pragma unroll
      for (int mb = 0; mb < 4; ++mb)
#pragma unroll
        for (int nb = 0; nb < 2; ++nb)
          sacc[mb][nb] = __builtin_amdgcn_mfma_f32_16x16x32_bf16(
              B[nb], qA[mb][h * 4 + k2], sacc[mb][nb], 0, 0, 0);
      __builtin_amdgcn_s_setprio(0);
    }
  };

  // prologue: tile 0 half 0 -> buf 0
  stage(0, kb);
  __syncthreads();

  for (int t = 0; t < NDT; ++t) {
    const size_t toff = (size_t)t * 64 * NH;
    const int dbase = dch * DCHUNK + t * 64 + wd * 32;

    // hoisted Vt B-frags for this tile's PV (drain under s0's barrier)
    bf16x8 vB[2];
#pragma unroll
    for (int cn = 0; cn < 2; ++cn)
      vB[cn] = *(const bf16x8*)(Vt + (size_t)(cn * 16 + l16) * ND + dbase + lg * 8);

#pragma unroll
    for (int mb = 0; mb < 4; ++mb) {
      sacc[mb][0] = f32x4{0.f, 0.f, 0.f, 0.f};
      sacc[mb][1] = f32x4{0.f, 0.f, 0.f, 0.f};
    }

    // s0: stage half1 -> buf1, compute half0 (buf0)
    stage(1, kb + toff + 128);
    compute(0, 0);
    __syncthreads();
    // s1: stage next tile half0 -> buf0, compute half1 (buf1)
    if (t < NDT - 1) stage(0, kb + toff + 64 * NH);
    compute(1, 1);
    __syncthreads();

    // ---- cube (fp32) -> bf16 pack -> permlane transpose -> PV MFMA ----
    // sacc[mb][nb]: q = l16, d = wd*32 + nb*16 + lg*4 + r.
#pragma unroll
    for (int mb = 0; mb < 4; ++mb) {
      f32x4 sx = sacc[mb][0];
      f32x4 sy = sacc[mb][1];
      f32x4 cx = sx * sx * sx;
      f32x4 cy = sy * sy * sy;
      unsigned x0 = cvtpk(cx[0], cx[1]);  // d = 4lg+0,1   (nb = 0)
      unsigned x1 = cvtpk(cx[2], cx[3]);  // d = 4lg+2,3
      unsigned y0 = cvtpk(cy[0], cy[1]);  // same, nb = 1
      unsigned y1 = cvtpk(cy[2], cy[3]);
      swap2(x0, y0);  // x0 -> a0 (k 8g+0,1), y0 -> a2 (k 8g+4,5)
      swap2(x1, y1);  // x1 -> a1 (k 8g+2,3), y1 -> a3 (k 8g+6,7)
      const int4 ai = {(int)x0, (int)x1, (int)y0, (int)y1};
      const bf16x8 aA = __builtin_bit_cast(bf16x8, ai);
#pragma unroll
      for (int cn = 0; cn < 2; ++cn)
        eacc[mb][cn] = __builtin_amdgcn_mfma_f32_16x16x32_bf16(
            aA, vB[cn], eacc[mb][cn], 0, 0, 0);
    }
    // PV touches no LDS/global; buffers protected by the s0/s1 barriers.
  }

  // ---- epilogue: merge wd=1 into wd=0 via LDS (K bufs dead), slot = dch ----
  float* eml = (float*)smem;  // [2 wr][64 lanes][36 dwords] = 18KB
  if (wd == 1) {
    float* dst = eml + (wr * 64 + lane) * 36;
#pragma unroll
    for (int mb = 0; mb < 4; ++mb)
#pragma unroll
      for (int cn = 0; cn < 2; ++cn)
        *(f32x4*)(dst + (mb * 2 + cn) * 4) = eacc[mb][cn];
  }
  __syncthreads();
  if (wd == 0) {
    const float* src = eml + (wr * 64 + lane) * 36;
#pragma unroll
    for (int mb = 0; mb < 4; ++mb)
#pragma unroll
      for (int cn = 0; cn < 2; ++cn) {
        const f32x4 m = eacc[mb][cn] + *(const f32x4*)(src + (mb * 2 + cn) * 4);
#pragma unroll
        for (int r = 0; r < 4; ++r) {
          const int row = rowbase + mb * 16 + lg * 4 + r;
          ep[((size_t)dch * NQ + row) * 32 + cn * 16 + l16] = m[r];
        }
      }
  }
}

// ---------------- reduce 8 partial slots -> d_out --------------------------
__global__ __launch_bounds__(256) void reduce_kernel(const float* __restrict__ ep,
                                                     float* __restrict__ out) {
  const int g = blockIdx.x * 256 + threadIdx.x;  // 8192*32
  const int q = g >> 5, c = g & 31;
  if (c < NC) {
    float s = 0.f;
#pragma unroll
    for (int k = 0; k < NSLOT; ++k) s += ep[((size_t)k * NQ + q) * 32 + c];
    out[(size_t)q * NC + c] = s;
  } else if (c == NC) {  // ones-column == intensity
    float s = 0.f;
#pragma unroll
    for (int k = 0; k < NSLOT; ++k) s += ep[((size_t)k * NQ + q) * 32 + NC];
    out[(size_t)NQ * NC + q] = s;
  }
}

extern "C" void kernel_launch(void* const* d_in, const int* in_sizes, int n_in,
                              void* d_out, int out_size, void* d_ws, size_t ws_size,
                              hipStream_t stream) {
  const float* feat = (const float*)d_in[0];  // [8192][256]
  const float* exf  = (const float*)d_in[1];  // [16384][256]
  const float* exc  = (const float*)d_in[2];  // [16384][28]
  float* out = (float*)d_out;
  char* ws = (char*)d_ws;
  // ws layout: qn 4MB | kn 8MB | vt 1MB | ep 8MB  (~21MB)
  u16* qn = (u16*)ws;
  u16* kn = (u16*)(ws + 4194304);
  u16* vt = (u16*)(ws + 12582912);
  float* ep = (float*)(ws + 13631488);

  prep_kernel<<<dim3(6208), dim3(256), 0, stream>>>(feat, exf, exc, qn, kn, vt);
  fused_kernel<<<dim3(512), dim3(256), 0, stream>>>(qn, kn, vt, ep);
  reduce_kernel<<<dim3(NQ * 32 / 256), dim3(256), 0, stream>>>(ep, out);
}